// Round 2
// baseline (1759.818 us; speedup 1.0000x reference)
//
#include <hip/hip_runtime.h>

// HPWL: per-net bounding-box half-perimeter, summed over masked non-empty nets.
//
// Trick: order-preserving float->uint encoding lets every reduction be
// atomicMax(unsigned). For mins we atomicMax the complement. Identity for
// all four arrays is 0, so one memsetAsync(0) initializes, and a stored
// value of 0 exactly flags "empty net" (no real float encodes to 0 or ~0).
//
// R1 lesson: net_mask (jnp bool) arrives as int32 words (value 0/1), NOT
// bytes — reading as uchar counted only every 4th net (exactly 1/4 of the
// reference sum, which matched the observed absmax error).

__device__ __forceinline__ unsigned enc(float f) {
    unsigned u = __float_as_uint(f);
    return u ^ ((unsigned)((int)u >> 31) | 0x80000000u);
}
__device__ __forceinline__ float dec(unsigned u) {
    unsigned b = (u & 0x80000000u) ? (u ^ 0x80000000u) : ~u;
    return __uint_as_float(b);
}

__device__ __forceinline__ void upd(unsigned* __restrict__ mx,
                                    unsigned* __restrict__ nx,
                                    unsigned* __restrict__ my,
                                    unsigned* __restrict__ ny,
                                    float x, float y, int net) {
    unsigned ex = enc(x), ey = enc(y);
    atomicMax(&mx[net], ex);
    atomicMax(&nx[net], ~ex);
    atomicMax(&my[net], ey);
    atomicMax(&ny[net], ~ey);
}

__global__ void pin_kernel(const float4* __restrict__ px,
                           const float4* __restrict__ py,
                           const int4* __restrict__ p2n,
                           unsigned* __restrict__ mx, unsigned* __restrict__ nx,
                           unsigned* __restrict__ my, unsigned* __restrict__ ny,
                           int n4) {
    int i = blockIdx.x * blockDim.x + threadIdx.x;
    if (i >= n4) return;
    float4 x = px[i];
    float4 y = py[i];
    int4 net = p2n[i];
    upd(mx, nx, my, ny, x.x, y.x, net.x);
    upd(mx, nx, my, ny, x.y, y.y, net.y);
    upd(mx, nx, my, ny, x.z, y.z, net.z);
    upd(mx, nx, my, ny, x.w, y.w, net.w);
}

// Tail handler for num_pins not divisible by 4 (not hit at 10M, kept for safety).
__global__ void pin_tail_kernel(const float* __restrict__ pos,
                                const int* __restrict__ p2n,
                                unsigned* __restrict__ mx, unsigned* __restrict__ nx,
                                unsigned* __restrict__ my, unsigned* __restrict__ ny,
                                int start, int num_pins) {
    int i = start + blockIdx.x * blockDim.x + threadIdx.x;
    if (i >= num_pins) return;
    upd(mx, nx, my, ny, pos[i], pos[i + num_pins], p2n[i]);
}

__global__ void net_kernel(const unsigned* __restrict__ mx,
                           const unsigned* __restrict__ nx,
                           const unsigned* __restrict__ my,
                           const unsigned* __restrict__ ny,
                           const int* __restrict__ mask,   // bool arrives as int32
                           float* __restrict__ out, int num_nets) {
    int i = blockIdx.x * blockDim.x + threadIdx.x;
    float h = 0.0f;
    if (i < num_nets) {
        unsigned a = mx[i];
        if (a != 0u && mask[i] != 0) {   // a==0 <=> empty net (counts==0)
            float xmax = dec(a);
            float xmin = dec(~nx[i]);
            float ymax = dec(my[i]);
            float ymin = dec(~ny[i]);
            h = (xmax - xmin) + (ymax - ymin);
        }
    }
    // wave (64-lane) reduction
    #pragma unroll
    for (int off = 32; off > 0; off >>= 1)
        h += __shfl_down(h, off);
    __shared__ float s[4];
    int wid = threadIdx.x >> 6;
    if ((threadIdx.x & 63) == 0) s[wid] = h;
    __syncthreads();
    if (threadIdx.x == 0) {
        float t = s[0] + s[1] + s[2] + s[3];
        atomicAdd(out, t);
    }
}

extern "C" void kernel_launch(void* const* d_in, const int* in_sizes, int n_in,
                              void* d_out, int out_size, void* d_ws, size_t ws_size,
                              hipStream_t stream) {
    const float* pos = (const float*)d_in[0];
    const int* p2n = (const int*)d_in[1];
    const int* mask = (const int*)d_in[2];
    const int num_pins = in_sizes[0] / 2;
    const int num_nets = in_sizes[2];

    unsigned* mx = (unsigned*)d_ws;
    unsigned* nx = mx + num_nets;
    unsigned* my = nx + num_nets;
    unsigned* ny = my + num_nets;

    // Init: all four reduction arrays to identity (0), output accumulator to 0.
    hipMemsetAsync(d_ws, 0, (size_t)4 * num_nets * sizeof(unsigned), stream);
    hipMemsetAsync(d_out, 0, sizeof(float), stream);

    const int threads = 256;
    const int n4 = num_pins / 4;
    if (n4 > 0) {
        int blocks = (n4 + threads - 1) / threads;
        pin_kernel<<<blocks, threads, 0, stream>>>(
            (const float4*)pos, (const float4*)(pos + num_pins), (const int4*)p2n,
            mx, nx, my, ny, n4);
    }
    const int tail_start = n4 * 4;
    if (tail_start < num_pins) {
        int tail = num_pins - tail_start;
        pin_tail_kernel<<<(tail + threads - 1) / threads, threads, 0, stream>>>(
            pos, p2n, mx, nx, my, ny, tail_start, num_pins);
    }
    net_kernel<<<(num_nets + threads - 1) / threads, threads, 0, stream>>>(
        mx, nx, my, ny, mask, (float*)d_out, num_nets);
}